// Round 17
// baseline (268.618 us; speedup 1.0000x reference)
//
#include <hip/hip_runtime.h>
#include <stdint.h>

// QuantizedLinear (BitNet ternary): out = x @ q^T + bias
// INT8 path (absmax 3.06). R16: B operand moved OUT of LDS — per-wave B
// fragments loaded global->VGPR (L2-resident via XCD col-chunk swizzle),
// register-double-buffered one tile ahead. LDS holds only A (3 bufs, 48 KiB):
// LDS traffic 128->80 KB/tile, below the MFMA floor. Counted vmcnt(8)/vmcnt(6)
// waits, never 0 in the main loop; guard-free 2-tile-unrolled loop.

#define M_DIM 8192
#define N_DIM 4096
#define K_DIM 4096
#define BM 256
#define BN 256
#define BK 64

typedef __attribute__((ext_vector_type(4))) int vi4;

#define BAR() asm volatile("s_barrier" ::: "memory")
#define VMW(n) asm volatile("s_waitcnt vmcnt(" #n ")" ::: "memory")
#define SB0() __builtin_amdgcn_sched_barrier(0)
#define LGKM0()                                             \
  do {                                                      \
    SB0();                                                  \
    asm volatile("s_waitcnt lgkmcnt(0)" ::: "memory");      \
    SB0();                                                  \
  } while (0)

__device__ __forceinline__ void load_lds16(const void* g, void* l) {
  __builtin_amdgcn_global_load_lds(
      (const __attribute__((address_space(1))) void*)g,
      (__attribute__((address_space(3))) void*)l,
      16, 0, 0);
}

// ---------- K1: per-block partial sums of |w| (deterministic) ----------
__global__ __launch_bounds__(256) void k_abs_partial(const float* __restrict__ w,
                                                     double* __restrict__ partial) {
  const int tid = threadIdx.x;
  const size_t base = (size_t)blockIdx.x * 8192 + (size_t)tid * 4;
  double s = 0.0;
#pragma unroll
  for (int it = 0; it < 8; ++it) {
    const float4 v = *reinterpret_cast<const float4*>(w + base + (size_t)it * 1024);
    s += (double)fabsf(v.x) + (double)fabsf(v.y) + (double)fabsf(v.z) + (double)fabsf(v.w);
  }
  __shared__ double sd[256];
  sd[tid] = s;
  __syncthreads();
  for (int off = 128; off > 0; off >>= 1) {
    if (tid < off) sd[tid] += sd[tid + off];
    __syncthreads();
  }
  if (tid == 0) partial[blockIdx.x] = sd[0];
}

// ---------- K2: finalize gamma (fp32 like numpy) ----------
__global__ __launch_bounds__(256) void k_abs_final(const double* __restrict__ partial,
                                                   float* __restrict__ gamma_out) {
  const int tid = threadIdx.x;
  double s = 0.0;
  for (int i = tid; i < 2048; i += 256) s += partial[i];
  __shared__ double sd[256];
  sd[tid] = s;
  __syncthreads();
  for (int off = 128; off > 0; off >>= 1) {
    if (tid < off) sd[tid] += sd[tid + off];
    __syncthreads();
  }
  if (tid == 0) {
    float g = (float)(sd[0] / 16777216.0);  // mean over 4096*4096
    gamma_out[0] = g + 1e-5f;
  }
}

// ---------- K3: quantize W -> ternary int8 ----------
__global__ __launch_bounds__(256) void k_quant(const float* __restrict__ w,
                                               const float* __restrict__ gamma_p,
                                               int* __restrict__ qb) {
  const float g = gamma_p[0];
  const size_t n4 = (size_t)N_DIM * K_DIM / 4;
  const size_t stride = (size_t)gridDim.x * blockDim.x;
  for (size_t i = (size_t)blockIdx.x * blockDim.x + threadIdx.x; i < n4; i += stride) {
    const float4 v = reinterpret_cast<const float4*>(w)[i];
    float r;
    int a, b, c, d;
    r = rintf(v.x / g); a = (r >= 1.0f) ? 1 : ((r <= -1.0f) ? -1 : 0);
    r = rintf(v.y / g); b = (r >= 1.0f) ? 1 : ((r <= -1.0f) ? -1 : 0);
    r = rintf(v.z / g); c = (r >= 1.0f) ? 1 : ((r <= -1.0f) ? -1 : 0);
    r = rintf(v.w / g); d = (r >= 1.0f) ? 1 : ((r <= -1.0f) ? -1 : 0);
    qb[i] = (a & 0xff) | ((b & 0xff) << 8) | ((c & 0xff) << 16) | ((d & 0xff) << 24);
  }
}

// ---------- K4: x fp32 -> per-row-scaled int8 ----------
__global__ __launch_bounds__(256) void k_quant_x(const float* __restrict__ x,
                                                 signed char* __restrict__ xq,
                                                 float* __restrict__ xs) {
  const int row = blockIdx.x;  // 8192
  const int tid = threadIdx.x;
  const float* xr = x + (size_t)row * K_DIM;
  float4 v[4];
  float am = 0.0f;
#pragma unroll
  for (int i = 0; i < 4; ++i) {
    v[i] = reinterpret_cast<const float4*>(xr)[tid * 4 + i];
    am = fmaxf(am, fmaxf(fmaxf(fabsf(v[i].x), fabsf(v[i].y)),
                         fmaxf(fabsf(v[i].z), fabsf(v[i].w))));
  }
  for (int off = 32; off > 0; off >>= 1) am = fmaxf(am, __shfl_down(am, off));
  __shared__ float sm[4];
  if ((tid & 63) == 0) sm[tid >> 6] = am;
  __syncthreads();
  const float bm = fmaxf(fmaxf(fmaxf(sm[0], sm[1]), fmaxf(sm[2], sm[3])), 1e-20f);
  if (tid == 0) xs[row] = bm / 127.0f;
  const float inv = 127.0f / bm;
  union { signed char c[16]; int4 q; } u;
#pragma unroll
  for (int i = 0; i < 4; ++i) {
    u.c[i * 4 + 0] = (signed char)(int)rintf(v[i].x * inv);
    u.c[i * 4 + 1] = (signed char)(int)rintf(v[i].y * inv);
    u.c[i * 4 + 2] = (signed char)(int)rintf(v[i].z * inv);
    u.c[i * 4 + 3] = (signed char)(int)rintf(v[i].w * inv);
  }
  *reinterpret_cast<int4*>(xq + (size_t)row * K_DIM + tid * 16) = u.q;
}

// ---------- K5: 256x256 i8 MFMA GEMM, A-only LDS, B global->reg ----------
// A LDS swizzle (verified R13/R15): 64B rows = 4x16B slots; logical slot c at
// phys slot c ^ ((row>>1)&3); inverse-swizzled glds source + swizzled ds_read.
__global__ __launch_bounds__(512, 2) void k_gemm(const signed char* __restrict__ Aq,
                                                 const signed char* __restrict__ Bq,
                                                 const float* __restrict__ xs,
                                                 const float* __restrict__ bias,
                                                 float* __restrict__ C) {
  __shared__ unsigned char lds[3][256][64];  // 48 KiB, A tiles only

  const int tid = threadIdx.x;
  const int wid = tid >> 6;   // 0..7
  const int lane = tid & 63;
  const int wm = wid >> 2;    // 0..1
  const int wn = wid & 3;     // 0..3
  const int l15 = lane & 15;
  const int l4 = lane >> 4;   // 0..3

  // bijective XCD col-chunk swizzle: 512 blocks = 8 XCDs x 64; XCD c owns
  // bx in {2c, 2c+1} (its 2 B col-panels = 2MB i8, L2-resident), all by.
  const int c8 = blockIdx.x & 7;
  const int idx = blockIdx.x >> 3;
  const int bcol = (c8 * 2 + (idx & 1)) * BN;
  const int brow = (idx >> 1) * BM;

  // A staging: lane covers (row = wid*16 + lane>>2, slot = lane&3) of a 128-row half
  const int srow = wid * 16 + (lane >> 2);
  const int scol = ((lane & 3) ^ ((lane >> 3) & 3)) << 4;  // inverse-swizzled src byte
  // ds_read: phys slot = l4 ^ ((row>>1)&3); row ≡ l15 (mod 8)
  const int rdoff = ((l4 ^ ((l15 >> 1) & 3)) << 4);

  // per-lane global B base: row (bcol + p*64 + wn*16 + l15), 16B at k-slot l4
  const signed char* bbase =
      Bq + (size_t)(bcol + wn * 16 + l15) * K_DIM + l4 * 16;

#define STAGE_A(buf, kt)                                                           \
  do {                                                                             \
    load_lds16(Aq + (size_t)(brow + srow) * K_DIM + (kt)*64 + scol,                \
               (char*)&lds[buf][0][0] + (size_t)wid * 1024);                       \
    load_lds16(Aq + (size_t)(brow + 128 + srow) * K_DIM + (kt)*64 + scol,          \
               (char*)&lds[buf][128][0] + (size_t)wid * 1024);                     \
    SB0();                                                                         \
  } while (0)

#define GLB_B(BR, kt)                                                              \
  do {                                                                             \
    _Pragma("unroll") for (int p = 0; p < 4; ++p)                                  \
      BR[p] = *reinterpret_cast<const vi4*>(                                       \
          bbase + (size_t)(p * 64) * K_DIM + (kt)*64);                             \
    SB0();                                                                         \
  } while (0)

#define RD_A8(F, buf)                                                              \
  do {                                                                             \
    _Pragma("unroll") for (int i = 0; i < 8; ++i)                                  \
      F[i] = *reinterpret_cast<const vi4*>(                                        \
          &lds[buf][0][0] + (size_t)(wm * 128 + i * 16 + l15) * 64 + rdoff);       \
    SB0();                                                                         \
  } while (0)

#define MFMA32(F, BR)                                                              \
  do {                                                                             \
    __builtin_amdgcn_s_setprio(1);                                                 \
    _Pragma("unroll") for (int i = 0; i < 8; ++i)                                  \
      _Pragma("unroll") for (int p = 0; p < 4; ++p)                                \
        acc[i][p] = __builtin_amdgcn_mfma_i32_16x16x64_i8(F[i], BR[p],             \
                                                          acc[i][p], 0, 0, 0);     \
    __builtin_amdgcn_s_setprio(0);                                                 \
  } while (0)

  vi4 acc[8][4];
#pragma unroll
  for (int i = 0; i < 8; ++i)
#pragma unroll
    for (int p = 0; p < 4; ++p)
#pragma unroll
      for (int e = 0; e < 4; ++e) acc[i][p][e] = 0;

  vi4 fr[8], bA[4], bB[4];

  // prologue: A(0)->buf0, A(1)->buf1, B(0)->bA; drain all once
  STAGE_A(0, 0);
  STAGE_A(1, 1);
  GLB_B(bA, 0);
  VMW(0);
  BAR();

  int cur = 0;  // buf holding tile t
  // steady loop: tiles (t, t+1), t = 0,2,...,60; no guards (t+3 <= 63)
  for (int t = 0; t < 62; t += 2) {
    const int b1 = (cur == 2) ? 0 : cur + 1;   // buf of t+1
    const int b2 = (b1 == 2) ? 0 : b1 + 1;     // buf of t+2 (stage target)
    // ---- tile t (B in bA) ----
    RD_A8(fr, cur);
    GLB_B(bB, t + 1);
    STAGE_A(b2, t + 2);
    VMW(8);   // B(t) landed (A(t+1)glds2 + B(t+1)4 + A(t+2)2 = 8 newer)
    LGKM0();  // A frags landed
    MFMA32(fr, bA);
    VMW(6);   // A(t+1) landed (B(t+1)4 + A(t+2)2 = 6 newer) -> publish
    BAR();
    // ---- tile t+1 (B in bB) ----
    RD_A8(fr, b1);
    GLB_B(bA, t + 2);
    STAGE_A(cur, t + 3);  // overwrites buf of tile t (reads drained pre-BAR)
    VMW(8);
    LGKM0();
    MFMA32(fr, bB);
    VMW(6);
    BAR();
    cur = b2;
  }

  // ---- tile 62 (cur = buf2 index, B in bA) ----
  RD_A8(fr, cur);
  GLB_B(bB, 63);
  VMW(6);   // B(62) landed (A(63)2 + B(63)4 = 6 newer)
  LGKM0();
  MFMA32(fr, bA);
  VMW(4);   // A(63) landed (B(63)4 newer)
  BAR();
  // ---- tile 63 ----
  {
    const int b1 = (cur == 2) ? 0 : cur + 1;
    RD_A8(fr, b1);
    VMW(0);  // B(63) landed
    LGKM0();
    MFMA32(fr, bB);
  }

  // ---- epilogue: C/D layout col=lane&15, row=(lane>>4)*4+j; dequant + bias ----
  float bi[4];
#pragma unroll
  for (int p = 0; p < 4; ++p) bi[p] = bias[bcol + p * 64 + wn * 16 + l15];
#pragma unroll
  for (int i = 0; i < 8; ++i) {
#pragma unroll
    for (int j = 0; j < 4; ++j) {
      const int row = brow + wm * 128 + i * 16 + l4 * 4 + j;
      const float sc = xs[row];
      float* crow = C + (size_t)row * N_DIM + bcol + wn * 16 + l15;
#pragma unroll
      for (int p = 0; p < 4; ++p) crow[p * 64] = (float)acc[i][p][j] * sc + bi[p];
    }
  }
#undef STAGE_A
#undef GLB_B
#undef RD_A8
#undef MFMA32
}

extern "C" void kernel_launch(void* const* d_in, const int* in_sizes, int n_in,
                              void* d_out, int out_size, void* d_ws, size_t ws_size,
                              hipStream_t stream) {
  (void)in_sizes; (void)n_in; (void)out_size; (void)ws_size;
  const float* x = (const float*)d_in[0];
  const float* w = (const float*)d_in[1];
  const float* bias = (const float*)d_in[2];
  float* out = (float*)d_out;

  char* ws = (char*)d_ws;
  signed char* xq = (signed char*)ws;                                   // 32 MB
  signed char* qb = (signed char*)(ws + (size_t)M_DIM * K_DIM);         // 16 MB
  float* xs = (float*)(ws + (size_t)M_DIM * K_DIM + (size_t)N_DIM * K_DIM);  // 32 KB
  double* partial = (double*)((char*)xs + M_DIM * sizeof(float));
  float* gamma = (float*)(partial + 2048);

  k_abs_partial<<<2048, 256, 0, stream>>>(w, partial);
  k_abs_final<<<1, 256, 0, stream>>>(partial, gamma);
  k_quant<<<2048, 256, 0, stream>>>(w, gamma, (int*)qb);
  k_quant_x<<<M_DIM, 256, 0, stream>>>(x, xq, xs);

  k_gemm<<<512, 512, 0, stream>>>(xq, qb, xs, bias, out);
}

// Round 18
// 215.083 us; speedup vs baseline: 1.2489x; 1.2489x over previous
//
#include <hip/hip_runtime.h>
#include <stdint.h>

// QuantizedLinear (BitNet ternary): out = x @ q^T + bias
// INT8 path (absmax 3.06). R18: back to LDS-B (R17's global-B gather refuted);
// block shrunk to 128x256 / wave tile 64x64 so acc=64 AGPR -> ~164 regs/wave
// -> 4 waves/SIMD capacity; LDS 3x24KB=72KB -> TWO blocks co-resident per CU.
// Cross-block dephasing overlaps one block's LDS phase with the other's MFMA.
// Verified i8 swizzle; 1 barrier/tile; counted VMW(3) publish; LGKM0 stagger.

#define M_DIM 8192
#define N_DIM 4096
#define K_DIM 4096
#define BM 128
#define BN 256
#define BK 64

typedef __attribute__((ext_vector_type(4))) int vi4;

#define BAR() asm volatile("s_barrier" ::: "memory")
#define VMW(n) asm volatile("s_waitcnt vmcnt(" #n ")" ::: "memory")
#define SB0() __builtin_amdgcn_sched_barrier(0)
#define LGKM0()                                             \
  do {                                                      \
    SB0();                                                  \
    asm volatile("s_waitcnt lgkmcnt(0)" ::: "memory");      \
    SB0();                                                  \
  } while (0)

__device__ __forceinline__ void load_lds16(const void* g, void* l) {
  __builtin_amdgcn_global_load_lds(
      (const __attribute__((address_space(1))) void*)g,
      (__attribute__((address_space(3))) void*)l,
      16, 0, 0);
}

// ---------- K1: per-block partial sums of |w| (deterministic) ----------
__global__ __launch_bounds__(256) void k_abs_partial(const float* __restrict__ w,
                                                     double* __restrict__ partial) {
  const int tid = threadIdx.x;
  const size_t base = (size_t)blockIdx.x * 8192 + (size_t)tid * 4;
  double s = 0.0;
#pragma unroll
  for (int it = 0; it < 8; ++it) {
    const float4 v = *reinterpret_cast<const float4*>(w + base + (size_t)it * 1024);
    s += (double)fabsf(v.x) + (double)fabsf(v.y) + (double)fabsf(v.z) + (double)fabsf(v.w);
  }
  __shared__ double sd[256];
  sd[tid] = s;
  __syncthreads();
  for (int off = 128; off > 0; off >>= 1) {
    if (tid < off) sd[tid] += sd[tid + off];
    __syncthreads();
  }
  if (tid == 0) partial[blockIdx.x] = sd[0];
}

// ---------- K2: finalize gamma (fp32 like numpy) ----------
__global__ __launch_bounds__(256) void k_abs_final(const double* __restrict__ partial,
                                                   float* __restrict__ gamma_out) {
  const int tid = threadIdx.x;
  double s = 0.0;
  for (int i = tid; i < 2048; i += 256) s += partial[i];
  __shared__ double sd[256];
  sd[tid] = s;
  __syncthreads();
  for (int off = 128; off > 0; off >>= 1) {
    if (tid < off) sd[tid] += sd[tid + off];
    __syncthreads();
  }
  if (tid == 0) {
    float g = (float)(sd[0] / 16777216.0);  // mean over 4096*4096
    gamma_out[0] = g + 1e-5f;
  }
}

// ---------- K3: quantize W -> ternary int8 ----------
__global__ __launch_bounds__(256) void k_quant(const float* __restrict__ w,
                                               const float* __restrict__ gamma_p,
                                               int* __restrict__ qb) {
  const float g = gamma_p[0];
  const size_t n4 = (size_t)N_DIM * K_DIM / 4;
  const size_t stride = (size_t)gridDim.x * blockDim.x;
  for (size_t i = (size_t)blockIdx.x * blockDim.x + threadIdx.x; i < n4; i += stride) {
    const float4 v = reinterpret_cast<const float4*>(w)[i];
    float r;
    int a, b, c, d;
    r = rintf(v.x / g); a = (r >= 1.0f) ? 1 : ((r <= -1.0f) ? -1 : 0);
    r = rintf(v.y / g); b = (r >= 1.0f) ? 1 : ((r <= -1.0f) ? -1 : 0);
    r = rintf(v.z / g); c = (r >= 1.0f) ? 1 : ((r <= -1.0f) ? -1 : 0);
    r = rintf(v.w / g); d = (r >= 1.0f) ? 1 : ((r <= -1.0f) ? -1 : 0);
    qb[i] = (a & 0xff) | ((b & 0xff) << 8) | ((c & 0xff) << 16) | ((d & 0xff) << 24);
  }
}

// ---------- K4: x fp32 -> per-row-scaled int8 ----------
__global__ __launch_bounds__(256) void k_quant_x(const float* __restrict__ x,
                                                 signed char* __restrict__ xq,
                                                 float* __restrict__ xs) {
  const int row = blockIdx.x;  // 8192
  const int tid = threadIdx.x;
  const float* xr = x + (size_t)row * K_DIM;
  float4 v[4];
  float am = 0.0f;
#pragma unroll
  for (int i = 0; i < 4; ++i) {
    v[i] = reinterpret_cast<const float4*>(xr)[tid * 4 + i];
    am = fmaxf(am, fmaxf(fmaxf(fabsf(v[i].x), fabsf(v[i].y)),
                         fmaxf(fabsf(v[i].z), fabsf(v[i].w))));
  }
  for (int off = 32; off > 0; off >>= 1) am = fmaxf(am, __shfl_down(am, off));
  __shared__ float sm[4];
  if ((tid & 63) == 0) sm[tid >> 6] = am;
  __syncthreads();
  const float bm = fmaxf(fmaxf(fmaxf(sm[0], sm[1]), fmaxf(sm[2], sm[3])), 1e-20f);
  if (tid == 0) xs[row] = bm / 127.0f;
  const float inv = 127.0f / bm;
  union { signed char c[16]; int4 q; } u;
#pragma unroll
  for (int i = 0; i < 4; ++i) {
    u.c[i * 4 + 0] = (signed char)(int)rintf(v[i].x * inv);
    u.c[i * 4 + 1] = (signed char)(int)rintf(v[i].y * inv);
    u.c[i * 4 + 2] = (signed char)(int)rintf(v[i].z * inv);
    u.c[i * 4 + 3] = (signed char)(int)rintf(v[i].w * inv);
  }
  *reinterpret_cast<int4*>(xq + (size_t)row * K_DIM + tid * 16) = u.q;
}

// ---------- K5: 128x256 i8 MFMA GEMM, 64x64 wave tiles, 2 blocks/CU ----------
// i8 LDS swizzle (verified R13/R15): 64B rows = 4x16B slots; logical slot c at
// phys slot c ^ ((row>>1)&3); inverse-swizzled glds source + swizzled ds_read.
// Per buffer: A[128][64] at 0 (8KB), B[256][64] at 8192 (16KB) = 24KB.
__global__ __launch_bounds__(512) void k_gemm(const signed char* __restrict__ Aq,
                                              const signed char* __restrict__ Bq,
                                              const float* __restrict__ xs,
                                              const float* __restrict__ bias,
                                              float* __restrict__ C) {
  __shared__ unsigned char lds[3][24576];  // 72 KiB total -> 2 blocks/CU

  const int tid = threadIdx.x;
  const int wid = tid >> 6;   // 0..7
  const int lane = tid & 63;
  const int wm = wid >> 2;    // 0..1 (row half)
  const int wn = wid & 3;     // 0..3 (col quarter)
  const int l15 = lane & 15;
  const int l4 = lane >> 4;   // 0..3

  // bijective XCD col-chunk swizzle: 1024 blocks = 8 XCDs x 128; XCD c owns
  // B col-panels {2c, 2c+1} (2MB i8, L2-resident); rows stream.
  const int c8 = blockIdx.x & 7;
  const int idx = blockIdx.x >> 3;            // 0..127
  const int bcol = (c8 * 2 + (idx & 1)) * BN;
  const int brow = (idx >> 1) * BM;           // 0..63 row blocks

  // staging: thread covers seg tid (row = tid>>2, slot = tid&3); one glds for A
  // (8KB), two for B (16KB). Source col pre-inverse-swizzled.
  const int srow = tid >> 2;
  const int scol = ((tid & 3) ^ ((tid >> 3) & 3)) << 4;
  // ds_read: phys slot = l4 ^ ((row>>1)&3); row ≡ l15 (mod 16)
  const int rdoff = ((l4 ^ ((l15 >> 1) & 3)) << 4);

#define STAGE_ALL(buf, kt)                                                          \
  do {                                                                              \
    load_lds16(Aq + (size_t)(brow + srow) * K_DIM + (kt)*64 + scol,                 \
               (char*)&lds[buf][0] + (size_t)wid * 1024);                           \
    load_lds16(Bq + (size_t)(bcol + srow) * K_DIM + (kt)*64 + scol,                 \
               (char*)&lds[buf][8192] + (size_t)wid * 1024);                        \
    load_lds16(Bq + (size_t)(bcol + 128 + srow) * K_DIM + (kt)*64 + scol,           \
               (char*)&lds[buf][16384] + (size_t)wid * 1024);                       \
    SB0();                                                                          \
  } while (0)

#define RD8(buf)                                                                    \
  do {                                                                              \
    _Pragma("unroll") for (int i = 0; i < 4; ++i)                                   \
      fa[i] = *reinterpret_cast<const vi4*>(                                        \
          &lds[buf][0] + (size_t)(wm * 64 + i * 16 + l15) * 64 + rdoff);            \
    _Pragma("unroll") for (int p = 0; p < 4; ++p)                                   \
      fb[p] = *reinterpret_cast<const vi4*>(                                        \
          &lds[buf][8192] + (size_t)(wn * 64 + p * 16 + l15) * 64 + rdoff);         \
    SB0();                                                                          \
  } while (0)

#define MFMA16()                                                                    \
  do {                                                                              \
    __builtin_amdgcn_s_setprio(1);                                                  \
    _Pragma("unroll") for (int i = 0; i < 4; ++i)                                   \
      _Pragma("unroll") for (int p = 0; p < 4; ++p)                                 \
        acc[i][p] = __builtin_amdgcn_mfma_i32_16x16x64_i8(fa[i], fb[p],             \
                                                          acc[i][p], 0, 0, 0);      \
    __builtin_amdgcn_s_setprio(0);                                                  \
  } while (0)

  vi4 acc[4][4];
#pragma unroll
  for (int i = 0; i < 4; ++i)
#pragma unroll
    for (int p = 0; p < 4; ++p)
#pragma unroll
      for (int e = 0; e < 4; ++e) acc[i][p][e] = 0;

  vi4 fa[4], fb[4];

  // prologue: tile0 -> buf0, tile1 -> buf1
  STAGE_ALL(0, 0);
  STAGE_ALL(1, 1);
  VMW(3);  // tile0's 3 (oldest) landed; tile1's 3 in flight
  BAR();

  int cur = 0;
  for (int t = 0; t < 62; ++t) {
    const int stg = (cur == 0) ? 2 : cur - 1;  // (t+2)%3
    RD8(cur);                // 8 ds_read_b128 (tile t)
    STAGE_ALL(stg, t + 2);   // 3 glds (tile t+2); WAR-safe (see analysis)
    LGKM0();                 // own frags landed; staging continues in flight
    MFMA16();
    VMW(3);                  // tile t+1's 3 landed (3 newest = t+2's) -> publish
    BAR();
    cur = (cur == 2) ? 0 : cur + 1;
  }
  // tile 62 (cur = 2): tile 63 already staged; publish it with a full drain
  RD8(cur);
  LGKM0();
  MFMA16();
  VMW(0);
  BAR();
  // tile 63 (buf 0)
  RD8(0);
  LGKM0();
  MFMA16();

  // ---- epilogue: C/D layout col=lane&15, row=(lane>>4)*4+j; dequant + bias ----
  float bi[4];
#pragma unroll
  for (int p = 0; p < 4; ++p) bi[p] = bias[bcol + wn * 64 + p * 16 + l15];
#pragma unroll
  for (int i = 0; i < 4; ++i) {
#pragma unroll
    for (int j = 0; j < 4; ++j) {
      const int row = brow + wm * 64 + i * 16 + l4 * 4 + j;
      const float sc = xs[row];
      float* crow = C + (size_t)row * N_DIM + bcol + wn * 64 + l15;
#pragma unroll
      for (int p = 0; p < 4; ++p) crow[p * 16] = (float)acc[i][p][j] * sc + bi[p];
    }
  }
#undef STAGE_ALL
#undef RD8
#undef MFMA16
}

extern "C" void kernel_launch(void* const* d_in, const int* in_sizes, int n_in,
                              void* d_out, int out_size, void* d_ws, size_t ws_size,
                              hipStream_t stream) {
  (void)in_sizes; (void)n_in; (void)out_size; (void)ws_size;
  const float* x = (const float*)d_in[0];
  const float* w = (const float*)d_in[1];
  const float* bias = (const float*)d_in[2];
  float* out = (float*)d_out;

  char* ws = (char*)d_ws;
  signed char* xq = (signed char*)ws;                                   // 32 MB
  signed char* qb = (signed char*)(ws + (size_t)M_DIM * K_DIM);         // 16 MB
  float* xs = (float*)(ws + (size_t)M_DIM * K_DIM + (size_t)N_DIM * K_DIM);  // 32 KB
  double* partial = (double*)((char*)xs + M_DIM * sizeof(float));
  float* gamma = (float*)(partial + 2048);

  k_abs_partial<<<2048, 256, 0, stream>>>(w, partial);
  k_abs_final<<<1, 256, 0, stream>>>(partial, gamma);
  k_quant<<<2048, 256, 0, stream>>>(w, gamma, (int*)qb);
  k_quant_x<<<M_DIM, 256, 0, stream>>>(x, xq, xs);

  k_gemm<<<1024, 512, 0, stream>>>(xq, qb, xs, bias, out);
}